// Round 17
// baseline (52.617 us; speedup 1.0000x reference)
//
#include <hip/hip_runtime.h>
#include <hip/hip_bf16.h>

#define NLVL 16
#define TSZ  16384
#define NB   8
#define NS   16          // style blocks (split-K width)

typedef _Float16 h8 __attribute__((ext_vector_type(8)));
typedef float    f4 __attribute__((ext_vector_type(4)));

#define MFMA16(A,B,C) __builtin_amdgcn_mfma_f32_16x16x32_f16(A,B,C,0,0,0)
#define GAINF 1.41421356237309515f

// floor(16 * exp(l*ln(16)/15)); fp64 rounding analysis: l=15 -> 255 (NOT 256).
__device__ const float RES_TAB[16] = {
  16.f, 19.f, 23.f, 27.f, 33.f, 40.f, 48.f, 58.f,
  70.f, 84.f, 101.f, 122.f, 147.f, 176.f, 212.f, 255.f
};

__device__ __forceinline__ float lrelu(float x) {
  float v = x < 0.0f ? 0.2f * x : x;
  return GAINF * v;
}
__device__ __forceinline__ float act(float x) { return fmaxf(x, 0.2f * x); }

__device__ __forceinline__ float tanh_fast(float x) {
  float t = __builtin_amdgcn_exp2f(x * 2.8853900817779268f);  // e^{2x}
  return 1.0f - 2.0f * __builtin_amdgcn_rcpf(t + 1.0f);
}

__device__ __forceinline__ unsigned pk(float a, float b) {
  union { decltype(__builtin_amdgcn_cvt_pkrtz(0.f, 0.f)) h; unsigned u; } U;
  U.h = __builtin_amdgcn_cvt_pkrtz(a, b);
  return U.u;
}
__device__ __forceinline__ unsigned pk_rne(float a, float b) {
  union { _Float16 h[2]; unsigned u; } U;
  U.h[0] = (_Float16)a; U.h[1] = (_Float16)b;
  return U.u;
}

// ---------------- hash-grid features (global path, FUSED fallback) ----------
__device__ __forceinline__ void hash4(const float* __restrict__ bt,
                                      int n, int l0, float* g8)
{
  const float inv = 1.0f / 256.0f;
  float cx = ((n >> 8) + 0.5f) * inv;
  float cy = ((n & 255) + 0.5f) * inv;
#pragma unroll
  for (int j = 0; j < 4; ++j) {
    float res = RES_TAB[l0 + j];
    float px = cx * res, py = cy * res;
    float fx0 = floorf(px), fy0 = floorf(py);
    float fx = px - fx0, fy = py - fy0;
    unsigned x0 = (unsigned)fx0, y0 = (unsigned)fy0;
    unsigned hy0 = y0 * 2654435761u;
    unsigned hy1 = (y0 + 1u) * 2654435761u;
    unsigned i00 = (x0 ^ hy0) & 16383u;
    unsigned i10 = ((x0 + 1u) ^ hy0) & 16383u;
    unsigned i01 = (x0 ^ hy1) & 16383u;
    unsigned i11 = ((x0 + 1u) ^ hy1) & 16383u;
    const float2* tb = (const float2*)(bt + (size_t)(l0 + j) * (TSZ * 2));
    float2 f00 = tb[i00], f10 = tb[i10], f01 = tb[i01], f11 = tb[i11];
    float wx0 = 1.0f - fx, wy0 = 1.0f - fy;
    float w00 = wx0 * wy0, w10 = fx * wy0, w01 = wx0 * fy, w11 = fx * fy;
    g8[2 * j]     = w00 * f00.x + w10 * f10.x + w01 * f01.x + w11 * f11.x;
    g8[2 * j + 1] = w00 * f00.y + w10 * f10.y + w01 * f01.y + w11 * f11.y;
  }
}
__device__ __forceinline__ void hash_features(const float* __restrict__ bt,
                                              int n, float* g)
{
#pragma unroll
  for (int q = 0; q < 4; ++q) hash4(bt, n, q * 4, g + 8 * q);
}

// ---------------- 16-block counting barrier (device-scope) -------------------
// cnt zeroed each launch by hipMemsetAsync before k_pre. Targets 16,32,48,64.
__device__ __forceinline__ void gbar(unsigned* cnt, unsigned target) {
  __syncthreads();
  if (threadIdx.x == 0) {
    __threadfence();                 // release: partials visible device-wide
    atomicAdd(cnt, 1u);
    while (atomicAdd(cnt, 0u) < target) __builtin_amdgcn_s_sleep(8);
    __threadfence();                 // acquire: see others' partials
  }
  __syncthreads();
}

// ---------------- fused pre-pass, 512 threads ---------------------------------
// grid(16 + 128):
//   blocks 0..15  : style pipeline, K-sliced; each block streams 1/16 of the
//                   weights and computes partials for ALL 8 batches (weights
//                   are batch-independent) -> ~85 KB/CU instead of 1 MB/CU.
//                   4 in-kernel barriers separate L0/L1/L2/proj/fold.
//   blocks 16..143: hash via LDS-staged f16 table (R16 path).
__global__ void __launch_bounds__(512) k_pre(
    const float* __restrict__ z,
    const float* __restrict__ mw0, const float* __restrict__ mb0,
    const float* __restrict__ mw1, const float* __restrict__ mb1,
    const float* __restrict__ mw2, const float* __restrict__ mb2,
    const float* __restrict__ bt,
    const float* __restrict__ w_mod, const float* __restrict__ b_mod,
    const float* __restrict__ a0w, const float* __restrict__ a0b,
    const float* __restrict__ w0,
    const float* __restrict__ a1w, const float* __restrict__ a1b,
    const float* __restrict__ w1,
    const float* __restrict__ a2w, const float* __restrict__ a2b,
    const float* __restrict__ w2,
    _Float16* __restrict__ W0h, _Float16* __restrict__ W1h,
    _Float16* __restrict__ W2h, _Float16* __restrict__ ghf,
    float* __restrict__ pA, float* __restrict__ pB,
    float* __restrict__ pP, unsigned* __restrict__ cnt)
{
  __shared__ __align__(16) unsigned smem[16384];   // 64 KB union

  const int t = threadIdx.x;

  if (blockIdx.x >= NS) {
    // ---------------- hash: one level per block, f16 table in LDS ----------
    const int hb  = blockIdx.x - NS;    // 0..127
    const int lvl = hb & 15;
    const int pg  = hb >> 4;            // x columns [pg*32, pg*32+32)
    const int gg  = lvl >> 2;
    const int sub = 2 * (lvl & 3);

    const float4* tb4 = (const float4*)(bt + (size_t)lvl * (TSZ * 2));
#pragma unroll
    for (int i = 0; i < 16; ++i) {      // 8192 float4 / 512 threads
      float4 v = tb4[i * 512 + t];
      int e = (i * 512 + t) * 2;
      smem[e]     = pk_rne(v.x, v.y);
      smem[e + 1] = pk_rne(v.z, v.w);
    }
    __syncthreads();

    const int y = t & 255, xsub = t >> 8;     // xsub 0..1
    const float res = RES_TAB[lvl];
    const float inv = 1.0f / 256.0f;
    float cy = (y + 0.5f) * inv;
    float py = cy * res;
    float fy0 = floorf(py);
    float fy = py - fy0;
    unsigned y0 = (unsigned)fy0;
    unsigned hy0 = y0 * 2654435761u;
    unsigned hy1 = (y0 + 1u) * 2654435761u;
    float wy0 = 1.0f - fy;
    const int cc = y & 15, th = y >> 4;

#pragma unroll
    for (int i = 0; i < 16; ++i) {
      int xo = xsub * 16 + i;                 // 0..31
      float cx = (pg * 32 + xo + 0.5f) * inv;
      float px = cx * res;
      float fx0 = floorf(px);
      float fx = px - fx0;
      unsigned x0 = (unsigned)fx0;
      unsigned i00 = (x0 ^ hy0) & 16383u;
      unsigned i10 = ((x0 + 1u) ^ hy0) & 16383u;
      unsigned i01 = (x0 ^ hy1) & 16383u;
      unsigned i11 = ((x0 + 1u) ^ hy1) & 16383u;
      union { unsigned u; _Float16 h[2]; } e00, e10, e01, e11;
      e00.u = smem[i00]; e10.u = smem[i10];
      e01.u = smem[i01]; e11.u = smem[i11];
      float wx0 = 1.0f - fx;
      float w00 = wx0 * wy0, w10 = fx * wy0, w01 = wx0 * fy, w11 = fx * fy;
      float gx = w00 * (float)e00.h[0] + w10 * (float)e10.h[0]
               + w01 * (float)e01.h[0] + w11 * (float)e11.h[0];
      float gy = w00 * (float)e00.h[1] + w10 * (float)e10.h[1]
               + w01 * (float)e01.h[1] + w11 * (float)e11.h[1];
      int tile = pg * 512 + xo * 16 + th;
      *(unsigned*)&ghf[(size_t)tile * 512 + (gg * 16 + cc) * 8 + sub] =
          pk_rne(gx, gy);
    }
    return;
  }

  // ---------------- style pipeline, block sid of 16 ----------------
  float* F = (float*)smem;
  float* zsl  = F;            // [0,256)    z slice [8][32]
  float* sAct = F + 256;      // [256,2304) activations [8][256]
  float* st0  = F + 2304;     // [2304,2560) [8][32]
  float* scf  = F + 2560;     // [2560,2816)
  float* st1  = F + 2816;     // [2816,3328) [8][64]
  float* st2  = F + 3328;     // [3328,3840)
  float* part = F + 4096;     // [4096,8192) [2][8][256]

  const int sid = blockIdx.x;
  const int j = t & 255, rh = t >> 8;

  // ---- stage 0: layer0 partials. rows [sid*32, sid*32+32), all 8 batches ----
  if (t < 256) zsl[t] = z[(t >> 5) * 512 + sid * 32 + (t & 31)];
  __syncthreads();
  {
    const int r0 = rh * 16;            // local row base within slice
    float wv[16];
#pragma unroll
    for (int u = 0; u < 16; ++u)
      wv[u] = mw0[(sid * 32 + r0 + u) * 256 + j];
    float acc[8] = {0,0,0,0,0,0,0,0};
#pragma unroll
    for (int u = 0; u < 16; ++u)
#pragma unroll
      for (int b = 0; b < 8; ++b)
        acc[b] = fmaf(zsl[b * 32 + r0 + u], wv[u], acc[b]);
#pragma unroll
    for (int b = 0; b < 8; ++b) part[(rh * 8 + b) * 256 + j] = acc[b];
  }
  __syncthreads();
  if (t < 256)
#pragma unroll
    for (int b = 0; b < 8; ++b)
      pA[(sid * 8 + b) * 256 + t] = part[b * 256 + t] + part[(8 + b) * 256 + t];
  gbar(cnt, 16);

  // ---- stage 1: reduce L0 -> sAct; layer1 partials rows [sid*16,+16) ----
  {
    const int bh = t >> 8;             // batches [bh*4, bh*4+4)
#pragma unroll
    for (int bi = 0; bi < 4; ++bi) {
      int b = bh * 4 + bi;
      float v = mb0[j];
#pragma unroll
      for (int s = 0; s < NS; ++s) v += pA[(s * 8 + b) * 256 + j];
      sAct[b * 256 + j] = lrelu(v);
    }
  }
  __syncthreads();
  {
    const int r0 = sid * 16 + rh * 8;
    float wv[8];
#pragma unroll
    for (int u = 0; u < 8; ++u) wv[u] = mw1[(r0 + u) * 256 + j];
    float acc[8] = {0,0,0,0,0,0,0,0};
#pragma unroll
    for (int u = 0; u < 8; ++u)
#pragma unroll
      for (int b = 0; b < 8; ++b)
        acc[b] = fmaf(sAct[b * 256 + r0 + u], wv[u], acc[b]);
#pragma unroll
    for (int b = 0; b < 8; ++b) part[(rh * 8 + b) * 256 + j] = acc[b];
  }
  __syncthreads();
  if (t < 256)
#pragma unroll
    for (int b = 0; b < 8; ++b)
      pB[(sid * 8 + b) * 256 + t] = part[b * 256 + t] + part[(8 + b) * 256 + t];
  gbar(cnt, 32);

  // ---- stage 2: reduce L1 -> sAct; layer2 partials -> pA ----
  {
    const int bh = t >> 8;
#pragma unroll
    for (int bi = 0; bi < 4; ++bi) {
      int b = bh * 4 + bi;
      float v = mb1[j];
#pragma unroll
      for (int s = 0; s < NS; ++s) v += pB[(s * 8 + b) * 256 + j];
      sAct[b * 256 + j] = lrelu(v);
    }
  }
  __syncthreads();
  {
    const int r0 = sid * 16 + rh * 8;
    float wv[8];
#pragma unroll
    for (int u = 0; u < 8; ++u) wv[u] = mw2[(r0 + u) * 256 + j];
    float acc[8] = {0,0,0,0,0,0,0,0};
#pragma unroll
    for (int u = 0; u < 8; ++u)
#pragma unroll
      for (int b = 0; b < 8; ++b)
        acc[b] = fmaf(sAct[b * 256 + r0 + u], wv[u], acc[b]);
#pragma unroll
    for (int b = 0; b < 8; ++b) part[(rh * 8 + b) * 256 + j] = acc[b];
  }
  __syncthreads();
  if (t < 256)
#pragma unroll
    for (int b = 0; b < 8; ++b)
      pA[(sid * 8 + b) * 256 + t] = part[b * 256 + t] + part[(8 + b) * 256 + t];
  gbar(cnt, 48);

  // ---- stage 3: reduce L2 -> sAct (= s); proj partials rows [sid*16,+16) ----
  {
    const int bh = t >> 8;
#pragma unroll
    for (int bi = 0; bi < 4; ++bi) {
      int b = bh * 4 + bi;
      float v = mb2[j];
#pragma unroll
      for (int s = 0; s < NS; ++s) v += pA[(s * 8 + b) * 256 + j];
      sAct[b * 256 + j] = lrelu(v);
    }
  }
  __syncthreads();
  if (t < 192) {
    const int c = t, r0 = sid * 16;
    float acc[8] = {0,0,0,0,0,0,0,0};
    for (int u = 0; u < 16; ++u) {
      int row = r0 + u;
      float w = (c < 32)  ? w_mod[row * 32 + c]
              : (c < 64)  ? a0w[row * 32 + (c - 32)]
              : (c < 128) ? a1w[row * 64 + (c - 64)]
                          : a2w[row * 64 + (c - 128)];
#pragma unroll
      for (int b = 0; b < 8; ++b)
        acc[b] = fmaf(sAct[b * 256 + row], w, acc[b]);
    }
#pragma unroll
    for (int b = 0; b < 8; ++b) pP[(sid * 8 + b) * 192 + c] = acc[b];
  }
  gbar(cnt, 64);

  // ---- stage 4: reduce proj -> styles; demods; fold this block's slice ----
  if (t < 256) {
    int b = t >> 5, i = t & 31;
    float am = b_mod[i], as = a0b[i];
#pragma unroll
    for (int s = 0; s < NS; ++s) {
      am += pP[(s * 8 + b) * 192 + i];
      as += pP[(s * 8 + b) * 192 + 32 + i];
    }
    scf[b * 32 + i] = 1.0f + am;
    st0[b * 32 + i] = as;
  }
  {
    int b = t >> 6, jj = t & 63;
    float v1 = a1b[jj], v2 = a2b[jj];
#pragma unroll
    for (int s = 0; s < NS; ++s) {
      v1 += pP[(s * 8 + b) * 192 + 64 + jj];
      v2 += pP[(s * 8 + b) * 192 + 128 + jj];
    }
    st1[b * 64 + jj] = v1;
    st2[b * 64 + jj] = v2;
  }
  __syncthreads();

  if (t < 32) {                        // W0h cols j = sid*4 + (t&3)
    int b = t >> 2, jo = t & 3, jw = sid * 4 + jo;
    if (jw < 64) {
      float acc = 1e-8f;
#pragma unroll
      for (int i = 0; i < 32; ++i) {
        float p = st0[b * 32 + i] * w0[i * 64 + jw];
        acc = fmaf(p, p, acc);
      }
      float dm = 1.0f / sqrtf(acc);
#pragma unroll
      for (int i = 0; i < 32; ++i)
        W0h[b * 2048 + jw * 32 + i] =
            (_Float16)(scf[b * 32 + i] * st0[b * 32 + i] * w0[i * 64 + jw] * dm);
    }
  } else if (t >= 64 && t < 96) {      // W1h cols j2 = sid*4 + ...
    int u = t - 64, b = u >> 2, j2 = sid * 4 + (u & 3);
    if (j2 < 64) {
      float acc = 1e-8f;
#pragma unroll
      for (int k = 0; k < 64; ++k) {
        float p = st1[b * 64 + k] * w1[k * 64 + j2];
        acc = fmaf(p, p, acc);
      }
      float dm = 1.0f / sqrtf(acc);
#pragma unroll
      for (int k = 0; k < 64; ++k)
        W1h[b * 4096 + j2 * 64 + k] =
            (_Float16)(GAINF * st1[b * 64 + k] * w1[k * 64 + j2] * dm);
    }
  } else if (t >= 128 && t < 136) {    // W2h channel ch = sid
    int b = t - 128, ch = sid;
    if (ch < 3) {
      float acc = 1e-8f;
#pragma unroll
      for (int k = 0; k < 64; ++k) {
        float p = st2[b * 64 + k] * w2[k * 3 + ch];
        acc = fmaf(p, p, acc);
      }
      float dm = 1.0f / sqrtf(acc);
#pragma unroll
      for (int k = 0; k < 64; ++k)
        W2h[b * 1024 + ch * 64 + k] =
            (_Float16)(GAINF * st2[b * 64 + k] * w2[k * 3 + ch] * dm);
    } else {
#pragma unroll
      for (int k = 0; k < 64; ++k)
        W2h[b * 1024 + ch * 64 + k] = (_Float16)0.0f;
    }
  }
}

// ============ fallback single-kernel style (small ws) ========================
__device__ __forceinline__ void map_layer(const float* __restrict__ xs_in,
                                          float* __restrict__ out_lds,
                                          const float* __restrict__ W,
                                          const float* __restrict__ bias,
                                          int K, int t,
                                          float* __restrict__ part)
{
  const int j4 = (t & 63) * 4;
  const int ks = t >> 6;
  const int chunk = K >> 3;
  const int kb = ks * chunk;
  f4 a0 = {0,0,0,0}, a1 = {0,0,0,0}, a2 = {0,0,0,0}, a3 = {0,0,0,0};
  for (int k0 = 0; k0 < chunk; k0 += 8) {
    f4 wr[8];
#pragma unroll
    for (int u = 0; u < 8; ++u)
      wr[u] = *(const f4*)&W[(kb + k0 + u) * 256 + j4];
    float xr[8];
#pragma unroll
    for (int u = 0; u < 8; ++u) xr[u] = xs_in[kb + k0 + u];
#pragma unroll
    for (int u = 0; u < 8; u += 4) {
      a0 += xr[u + 0] * wr[u + 0];
      a1 += xr[u + 1] * wr[u + 1];
      a2 += xr[u + 2] * wr[u + 2];
      a3 += xr[u + 3] * wr[u + 3];
    }
  }
  *(f4*)&part[ks * 256 + j4] = (a0 + a1) + (a2 + a3);
  __syncthreads();
  if (t < 256) {
    float v = 0.f;
#pragma unroll
    for (int q = 0; q < 8; ++q) v += part[q * 256 + t];
    out_lds[t] = lrelu(bias[t] + v);
  }
  __syncthreads();
}

__global__ void __launch_bounds__(512) k_style1(
    const float* __restrict__ z,
    const float* __restrict__ mw0, const float* __restrict__ mb0,
    const float* __restrict__ mw1, const float* __restrict__ mb1,
    const float* __restrict__ mw2, const float* __restrict__ mb2,
    const float* __restrict__ w_mod, const float* __restrict__ b_mod,
    const float* __restrict__ a0w, const float* __restrict__ a0b,
    const float* __restrict__ w0,
    const float* __restrict__ a1w, const float* __restrict__ a1b,
    const float* __restrict__ w1,
    const float* __restrict__ a2w, const float* __restrict__ a2b,
    const float* __restrict__ w2,
    _Float16* __restrict__ W0h, _Float16* __restrict__ W1h,
    _Float16* __restrict__ W2h)
{
  __shared__ __align__(16) float F[8192];
  float* xs   = F;
  float* sA   = F + 512;
  float* sB   = F + 768;
  float* st0  = F + 1024;
  float* scf  = F + 1056;
  float* st1  = F + 1088;
  float* st2  = F + 1152;
  float* dm0  = F + 1216;
  float* dm1  = F + 1280;
  float* dm2  = F + 1344;
  float* part = F + 2048;
  const int t = threadIdx.x;
  const int b = blockIdx.x;

  xs[t] = z[b * 512 + t];
  __syncthreads();
  map_layer(xs, sA, mw0, mb0, 512, t, part);
  map_layer(sA, sB, mw1, mb1, 256, t, part);
  map_layer(sB, xs, mw2, mb2, 256, t, part);
  const float* ss = xs;

  {
    const int jg = (t & 7) * 4, kc = t >> 3, kb = kc * 4;
    f4 am = {0,0,0,0}, as = {0,0,0,0};
#pragma unroll
    for (int k = 0; k < 4; ++k) {
      float sv = ss[kb + k];
      am += sv * *(const f4*)&w_mod[(kb + k) * 32 + jg];
      as += sv * *(const f4*)&a0w[(kb + k) * 32 + jg];
    }
    *(f4*)&part[kc * 32 + jg] = am;
    *(f4*)&part[2048 + kc * 32 + jg] = as;
  }
  __syncthreads();
  if (t < 32) {
    float am = b_mod[t], as = a0b[t];
#pragma unroll
    for (int q = 0; q < 64; ++q) { am += part[q * 32 + t]; as += part[2048 + q * 32 + t]; }
    scf[t] = 1.0f + am; st0[t] = as;
  }
  __syncthreads();
  {
    const int jg = (t & 15) * 4, kc = t >> 4, kb = kc * 8;
    f4 v1 = {0,0,0,0}, v2 = {0,0,0,0};
#pragma unroll
    for (int k = 0; k < 8; ++k) {
      float sv = ss[kb + k];
      v1 += sv * *(const f4*)&a1w[(kb + k) * 64 + jg];
      v2 += sv * *(const f4*)&a2w[(kb + k) * 64 + jg];
    }
    *(f4*)&part[kc * 64 + jg] = v1;
    *(f4*)&part[2048 + kc * 64 + jg] = v2;
  }
  __syncthreads();
  if (t >= 128 && t < 192) {
    int jj = t - 128;
    float v1 = a1b[jj], v2 = a2b[jj];
#pragma unroll
    for (int q = 0; q < 32; ++q) { v1 += part[q * 64 + jj]; v2 += part[2048 + q * 64 + jj]; }
    st1[jj] = v1; st2[jj] = v2;
  }
  __syncthreads();
  if (t < 64) {
    float acc = 1e-8f;
    for (int i = 0; i < 32; ++i) { float p = st0[i] * w0[i * 64 + t]; acc = fmaf(p, p, acc); }
    dm0[t] = 1.0f / sqrtf(acc);
  } else if (t < 128) {
    int jj = t - 64; float acc = 1e-8f;
    for (int k = 0; k < 64; ++k) { float p = st1[k] * w1[k * 64 + jj]; acc = fmaf(p, p, acc); }
    dm1[jj] = 1.0f / sqrtf(acc);
  } else if (t >= 192 && t < 195) {
    int ch = t - 192; float acc = 1e-8f;
    for (int k = 0; k < 64; ++k) { float p = st2[k] * w2[k * 3 + ch]; acc = fmaf(p, p, acc); }
    dm2[ch] = 1.0f / sqrtf(acc);
  }
  __syncthreads();
  for (int f = t; f < 2048; f += 512) {
    int jw = f >> 5, i = f & 31;
    W0h[b * 2048 + f] = (_Float16)(scf[i] * st0[i] * w0[i * 64 + jw] * dm0[jw]);
  }
  for (int f = t; f < 4096; f += 512) {
    int j2 = f >> 6, k = f & 63;
    W1h[b * 4096 + f] = (_Float16)(GAINF * st1[k] * w1[k * 64 + j2] * dm1[j2]);
  }
  for (int f = t; f < 1024; f += 512) {
    int ch = f >> 6, k = f & 63;
    W2h[b * 1024 + f] = (ch < 3) ? (_Float16)(GAINF * st2[k] * w2[k * 3 + ch] * dm2[ch])
                                 : (_Float16)0.0f;
  }
}

// ---------------- LDS activation staging helpers ----------------------------
__device__ __forceinline__ void st4(_Float16* L, int pix, int jb, f4 v) {
  int ks = jb ^ ((pix & 7) << 3);
  union { unsigned u[2]; uint2 v2; } U;
  U.u[0] = pk(v[0], v[1]); U.u[1] = pk(v[2], v[3]);
  *(uint2*)(L + pix * 64 + ks) = U.v2;
}
__device__ __forceinline__ h8 ldf(const _Float16* L, int pix, int kb) {
  int ks = kb ^ ((pix & 7) << 3);
  return *(const h8*)(L + pix * 64 + ks);
}

// ---------------- MFMA MLP ---------------------------------------------------
template <int FUSED>
__global__ void __launch_bounds__(256) k_mlp(
    const _Float16* __restrict__ W0h, const _Float16* __restrict__ W1h,
    const _Float16* __restrict__ W2h, const _Float16* __restrict__ ghf,
    const float* __restrict__ bt,
    const float* __restrict__ bb0, const float* __restrict__ bb1,
    const float* __restrict__ bb2, float* __restrict__ out)
{
  __shared__ _Float16 lds[4][4096];
  __shared__ _Float16 hb[FUSED ? 8192 : 8];

  const int t = threadIdx.x;
  const int w = t >> 6, lane = t & 63;
  const int c = lane & 15, g = lane >> 4;
  const int b = blockIdx.y;
  const int pixb = blockIdx.x * 256 + w * 64;
  const int tile0 = pixb >> 4;
  _Float16* L = lds[w];

  if constexpr (FUSED) {
    float gl[32];
    hash_features(bt, blockIdx.x * 256 + t, gl);
    int tl = t >> 4, cl = t & 15;
#pragma unroll
    for (int gg = 0; gg < 4; ++gg) {
      union { unsigned u[4]; uint4 v; } U;
      U.u[0] = pk(gl[8 * gg + 0], gl[8 * gg + 1]);
      U.u[1] = pk(gl[8 * gg + 2], gl[8 * gg + 3]);
      U.u[2] = pk(gl[8 * gg + 4], gl[8 * gg + 5]);
      U.u[3] = pk(gl[8 * gg + 6], gl[8 * gg + 7]);
      *(uint4*)&hb[tl * 512 + (gg * 16 + cl) * 8] = U.v;
    }
    __syncthreads();
  }

  h8 A0[4], A1[4][2], A2[2];
#pragma unroll
  for (int jt = 0; jt < 4; ++jt)
    A0[jt] = *(const h8*)&W0h[b * 2048 + (jt * 16 + c) * 32 + 8 * g];
#pragma unroll
  for (int jt = 0; jt < 4; ++jt)
#pragma unroll
    for (int kf = 0; kf < 2; ++kf)
      A1[jt][kf] = *(const h8*)&W1h[b * 4096 + (jt * 16 + c) * 64 + kf * 32 + 8 * g];
#pragma unroll
  for (int kf = 0; kf < 2; ++kf)
    A2[kf] = *(const h8*)&W2h[b * 1024 + c * 64 + kf * 32 + 8 * g];

  f4 bv0[4], bv1[4], bv2;
#pragma unroll
  for (int jt = 0; jt < 4; ++jt) {
    bv0[jt] = *(const f4*)&bb0[jt * 16 + 4 * g];
    bv1[jt] = *(const f4*)&bb1[jt * 16 + 4 * g];
  }
  if (g == 0) { bv2 = f4{bb2[0], bb2[1], bb2[2], 0.0f}; }
  else        { bv2 = f4{0.0f, 0.0f, 0.0f, 0.0f}; }

  f4 acc[4][4];
#pragma unroll
  for (int pt = 0; pt < 4; ++pt) {
    h8 Bh;
    if constexpr (FUSED) {
      Bh = *(const h8*)&hb[(w * 4 + pt) * 512 + lane * 8];
    } else {
      Bh = *(const h8*)&ghf[(size_t)(tile0 + pt) * 512 + lane * 8];
    }
#pragma unroll
    for (int jt = 0; jt < 4; ++jt)
      acc[jt][pt] = MFMA16(A0[jt], Bh, bv0[jt]);
  }

#pragma unroll
  for (int jt = 0; jt < 4; ++jt)
#pragma unroll
    for (int pt = 0; pt < 4; ++pt) {
      f4 v = acc[jt][pt];
#pragma unroll
      for (int r = 0; r < 4; ++r) v[r] = act(v[r]);
      st4(L, pt * 16 + c, jt * 16 + 4 * g, v);
    }

  f4 acc1[4][4];
#pragma unroll
  for (int pt = 0; pt < 4; ++pt) {
    h8 Bf0 = ldf(L, pt * 16 + c, 0 * 32 + 8 * g);
    h8 Bf1 = ldf(L, pt * 16 + c, 1 * 32 + 8 * g);
#pragma unroll
    for (int jt = 0; jt < 4; ++jt) {
      f4 a = MFMA16(A1[jt][0], Bf0, bv1[jt]);
      acc1[jt][pt] = MFMA16(A1[jt][1], Bf1, a);
    }
  }

#pragma unroll
  for (int jt = 0; jt < 4; ++jt)
#pragma unroll
    for (int pt = 0; pt < 4; ++pt) {
      f4 v = acc1[jt][pt];
#pragma unroll
      for (int r = 0; r < 4; ++r) v[r] = act(v[r]);
      st4(L, pt * 16 + c, jt * 16 + 4 * g, v);
    }

#pragma unroll
  for (int pt = 0; pt < 4; ++pt) {
    h8 Bf0 = ldf(L, pt * 16 + c, 0 * 32 + 8 * g);
    h8 Bf1 = ldf(L, pt * 16 + c, 1 * 32 + 8 * g);
    f4 a = MFMA16(A2[0], Bf0, bv2);
    a = MFMA16(A2[1], Bf1, a);
    if (g == 0) {
      int pix = pixb + pt * 16 + c;
#pragma unroll
      for (int r = 0; r < 3; ++r)
        out[((b * 3 + r) << 16) + pix] = tanh_fast(a[r]);
    }
  }
}

// ---------------- launch -----------------------------------------------------
// ws bytes: [0,32768) W0h | [32768,98304) W1h | [98304,114688) W2h |
//   [114688,4308992) ghf | [4308992,4440064) pA (16x8x256 f) |
//   [4440064,4571136) pB | [4571136,4669440) pP (16x8x192 f) |
//   [4669440,4669448) barrier counter (zeroed via hipMemsetAsync each call)
extern "C" void kernel_launch(void* const* d_in, const int* in_sizes, int n_in,
                              void* d_out, int out_size, void* d_ws, size_t ws_size,
                              hipStream_t stream)
{
  const float* z    = (const float*)d_in[0];
  const float* mw0  = (const float*)d_in[1];
  const float* mb0  = (const float*)d_in[2];
  const float* mw1  = (const float*)d_in[3];
  const float* mb1  = (const float*)d_in[4];
  const float* mw2  = (const float*)d_in[5];
  const float* mb2  = (const float*)d_in[6];
  const float* bt   = (const float*)d_in[7];
  const float* wmod = (const float*)d_in[8];
  const float* bmod = (const float*)d_in[9];
  const float* a0w  = (const float*)d_in[10];
  const float* a0b  = (const float*)d_in[11];
  const float* w0   = (const float*)d_in[12];
  const float* bb0  = (const float*)d_in[13];
  const float* a1w  = (const float*)d_in[14];
  const float* a1b  = (const float*)d_in[15];
  const float* w1   = (const float*)d_in[16];
  const float* bb1  = (const float*)d_in[17];
  const float* a2w  = (const float*)d_in[18];
  const float* a2b  = (const float*)d_in[19];
  const float* w2   = (const float*)d_in[20];
  const float* bb2  = (const float*)d_in[21];

  char* ws = (char*)d_ws;
  _Float16* W0h = (_Float16*)(ws);
  _Float16* W1h = (_Float16*)(ws + 32768);
  _Float16* W2h = (_Float16*)(ws + 98304);
  _Float16* ghf = (_Float16*)(ws + 114688);
  float*    pA  = (float*)(ws + 4308992);
  float*    pB  = (float*)(ws + 4440064);
  float*    pP  = (float*)(ws + 4571136);
  unsigned* cnt = (unsigned*)(ws + 4669440);
  float* out = (float*)d_out;

  if (ws_size >= (size_t)4669448) {
    hipMemsetAsync(cnt, 0, 8, stream);   // barrier counter init (replay-safe)
    k_pre<<<NS + 128, 512, 0, stream>>>(z, mw0, mb0, mw1, mb1, mw2, mb2, bt,
                                        wmod, bmod, a0w, a0b, w0,
                                        a1w, a1b, w1, a2w, a2b, w2,
                                        W0h, W1h, W2h, ghf, pA, pB, pP, cnt);
    k_mlp<0><<<dim3(256, NB), 256, 0, stream>>>(W0h, W1h, W2h, ghf, bt,
                                                bb0, bb1, bb2, out);
  } else {
    k_style1<<<NB, 512, 0, stream>>>(z, mw0, mb0, mw1, mb1, mw2, mb2,
                                     wmod, bmod, a0w, a0b, w0,
                                     a1w, a1b, w1, a2w, a2b, w2,
                                     W0h, W1h, W2h);
    k_mlp<1><<<dim3(256, NB), 256, 0, stream>>>(W0h, W1h, W2h, ghf, bt,
                                                bb0, bb1, bb2, out);
  }
}